// Round 1
// baseline (567.283 us; speedup 1.0000x reference)
//
#include <hip/hip_runtime.h>

#define THRESHOLD 0.4f
#define HM_H 128
#define HM_W 128

// Two (b,k) items per thread: coords loaded as int4 (two (u,v) pairs, 16B
// coalesced), two INDEPENDENT heatmap gathers in flight per thread (ILP-2),
// output stored as int2. Semantics identical to the verified 1-item/thread
// version: flip (u,v)->(v,u), bounds-check, gather at clipped index, emit
// (in_bounds && val > THRESHOLD) as int32 0/1.
__global__ __launch_bounds__(128) void VisibilityHeatmap_41841571398294_kernel(
    const int4* __restrict__ coords2,     // [n/2] two pairs: (u0,v0,u1,v1)
    const float* __restrict__ heatmaps,   // [n, H, W]
    int2* __restrict__ out2,              // [n/2] int32 bool mask pairs
    int npairs)                            // n/2
{
    int t = blockIdx.x * blockDim.x + threadIdx.x;
    if (t >= npairs) return;

    int4 c = coords2[t];                  // items 2t and 2t+1
    int u0 = c.x, v0 = c.y;
    int u1 = c.z, v1 = c.w;

    bool ib0 = (v0 > -1) & (u0 > -1) & (v0 < HM_H) & (u0 < HM_W);
    bool ib1 = (v1 > -1) & (u1 > -1) & (v1 < HM_H) & (u1 < HM_W);

    int vc0 = min(max(v0, 0), HM_H - 1);
    int uc0 = min(max(u0, 0), HM_W - 1);
    int vc1 = min(max(v1, 0), HM_H - 1);
    int uc1 = min(max(u1, 0), HM_W - 1);

    size_t base = (size_t)(2 * t) * (HM_H * HM_W);
    // Two independent gathers — both issue before either s_waitcnt.
    float val0 = heatmaps[base + vc0 * HM_W + uc0];
    float val1 = heatmaps[base + (HM_H * HM_W) + vc1 * HM_W + uc1];

    int2 r;
    r.x = (ib0 && (val0 > THRESHOLD)) ? 1 : 0;
    r.y = (ib1 && (val1 > THRESHOLD)) ? 1 : 0;
    out2[t] = r;
}

extern "C" void kernel_launch(void* const* d_in, const int* in_sizes, int n_in,
                              void* d_out, int out_size, void* d_ws, size_t ws_size,
                              hipStream_t stream) {
    const int4*  coords2  = (const int4*)d_in[0];    // int32 [B,K,2] -> int4 pair-of-pairs
    const float* heatmaps = (const float*)d_in[1];   // float32 [B,K,H,W]
    int2*        out2     = (int2*)d_out;            // bool mask as int32, paired

    int n = in_sizes[0] / 2;   // B*K items (16384 ints -> 8192 pairs)
    int npairs = n / 2;        // 4096 threads, 2 items each (n is even: B*K=8192)

    int block = 128;
    int grid = (npairs + block - 1) / block;  // 32 blocks
    VisibilityHeatmap_41841571398294_kernel<<<grid, block, 0, stream>>>(
        coords2, heatmaps, out2, npairs);
}